// Round 1
// baseline (886.005 us; speedup 1.0000x reference)
//
#include <hip/hip_runtime.h>
#include <math.h>

// GCN 2-layer, algebraically fused:
//   L1: A_norm @ (x W1) + b1 == ((A_norm @ x) W1) + b1   -> aggregate 2-wide x
//   h  = relu(...)
//   L2: A_norm @ (h W2) + b2 == (A_norm @ (h W2)) + b2   -> aggregate 2-wide g = h@W2
//   out = log_softmax(...)
// A_norm has self loops, symmetric rsqrt(deg) norm; deg counted at dst.

#define BLK 256

__global__ void k_init_deg(float* __restrict__ deg, int n) {
    int i = blockIdx.x * BLK + threadIdx.x;
    if (i < n) deg[i] = 1.0f;   // self loop
}

__global__ void k_count_deg(const int* __restrict__ dst, float* __restrict__ deg, int e) {
    int i = blockIdx.x * BLK + threadIdx.x;
    if (i < e) atomicAdd(&deg[dst[i]], 1.0f);
}

// deg -> dinv (in place); init agg_x with self-loop term dinv^2 * x
__global__ void k_dinv_self(const float* __restrict__ x, float* __restrict__ deg_dinv,
                            float* __restrict__ agg_x, int n) {
    int i = blockIdx.x * BLK + threadIdx.x;
    if (i < n) {
        float d = rsqrtf(deg_dinv[i]);  // deg >= 1 always
        deg_dinv[i] = d;
        float s = d * d;
        float2 xv = ((const float2*)x)[i];
        ((float2*)agg_x)[i] = make_float2(s * xv.x, s * xv.y);
    }
}

// agg[dst] += dinv[src]*dinv[dst] * feat[src]   (feat is [n,2])
__global__ void k_edge_agg(const int* __restrict__ src, const int* __restrict__ dst,
                           const float* __restrict__ dinv, const float* __restrict__ feat,
                           float* __restrict__ agg, int e) {
    int i = blockIdx.x * BLK + threadIdx.x;
    if (i < e) {
        int s = src[i];
        int d = dst[i];
        float nrm = dinv[s] * dinv[d];
        float2 f = ((const float2*)feat)[s];
        atomicAdd(&agg[2 * d + 0], nrm * f.x);
        atomicAdd(&agg[2 * d + 1], nrm * f.y);
    }
}

// per node: h = relu(agg_x @ W1 + b1); g = h @ W2; agg_g init = dinv^2 * g
__global__ void k_mlp(const float* __restrict__ agg_x, const float* __restrict__ dinv,
                      const float* __restrict__ W1, const float* __restrict__ b1,
                      const float* __restrict__ W2,
                      float* __restrict__ g, float* __restrict__ agg_g, int n) {
    int i = blockIdx.x * BLK + threadIdx.x;
    if (i < n) {
        float2 a = ((const float2*)agg_x)[i];
        float g0 = 0.f, g1 = 0.f;
#pragma unroll
        for (int f = 0; f < 16; ++f) {
            float h = fmaf(a.x, W1[f], fmaf(a.y, W1[16 + f], b1[f]));
            h = fmaxf(h, 0.0f);
            g0 = fmaf(h, W2[2 * f + 0], g0);
            g1 = fmaf(h, W2[2 * f + 1], g1);
        }
        ((float2*)g)[i] = make_float2(g0, g1);
        float s = dinv[i] * dinv[i];
        ((float2*)agg_g)[i] = make_float2(s * g0, s * g1);
    }
}

__global__ void k_logsoftmax(const float* __restrict__ agg_g, const float* __restrict__ b2,
                             float* __restrict__ out, int n) {
    int i = blockIdx.x * BLK + threadIdx.x;
    if (i < n) {
        float2 z = ((const float2*)agg_g)[i];
        float z0 = z.x + b2[0];
        float z1 = z.y + b2[1];
        float m = fmaxf(z0, z1);
        float lse = m + logf(expf(z0 - m) + expf(z1 - m));
        ((float2*)out)[i] = make_float2(z0 - lse, z1 - lse);
    }
}

extern "C" void kernel_launch(void* const* d_in, const int* in_sizes, int n_in,
                              void* d_out, int out_size, void* d_ws, size_t ws_size,
                              hipStream_t stream) {
    const float* x  = (const float*)d_in[0];   // [n,2]
    const int*   ei = (const int*)d_in[1];     // [2,e] flat: row0=src, row1=dst
    const float* W1 = (const float*)d_in[2];   // [2,16]
    const float* b1 = (const float*)d_in[3];   // [16]
    const float* W2 = (const float*)d_in[4];   // [16,2]
    const float* b2 = (const float*)d_in[5];   // [2]
    float* out = (float*)d_out;                // [n,2]

    const int n = in_sizes[0] / 2;             // 100000
    const int e = in_sizes[1] / 2;             // 3200000
    const int* src = ei;
    const int* dst = ei + e;

    // ws layout (floats): dinv [n] | agg_x [2n] | g [2n] | agg_g [2n]  (~2.8 MB)
    float* ws    = (float*)d_ws;
    float* dinv  = ws;
    float* agg_x = ws + (size_t)n;
    float* g     = ws + 3 * (size_t)n;
    float* agg_g = ws + 5 * (size_t)n;

    const int gn = (n + BLK - 1) / BLK;
    const int ge = (e + BLK - 1) / BLK;

    k_init_deg  <<<gn, BLK, 0, stream>>>(dinv, n);
    k_count_deg <<<ge, BLK, 0, stream>>>(dst, dinv, e);
    k_dinv_self <<<gn, BLK, 0, stream>>>(x, dinv, agg_x, n);
    k_edge_agg  <<<ge, BLK, 0, stream>>>(src, dst, dinv, x, agg_x, e);      // layer-1 agg of raw x
    k_mlp       <<<gn, BLK, 0, stream>>>(agg_x, dinv, W1, b1, W2, g, agg_g, n);
    k_edge_agg  <<<ge, BLK, 0, stream>>>(src, dst, dinv, g, agg_g, e);      // layer-2 agg of g
    k_logsoftmax<<<gn, BLK, 0, stream>>>(agg_g, b2, out, n);
}

// Round 3
// 416.190 us; speedup vs baseline: 2.1288x; 2.1288x over previous
//
#include <hip/hip_runtime.h>
#include <math.h>

// GCN 2-layer, algebraically fused, ATOMIC-FREE (global):
//   L1: A_norm @ (x W1) + b1 == ((A_norm @ x) W1) + b1   -> aggregate 2-wide x
//   h  = relu(...)
//   L2: A_norm @ (h W2) + b2 == (A_norm @ (h W2)) + b2   -> aggregate 2-wide g = h@W2
//   out = log_softmax(...)
//
// R2: global fp atomics (20/ns transaction-rate wall, 200MB write-through) replaced
// by bucketed counting sort (256 nodes/bucket = dst>>8) + per-bucket LDS aggregation.
// Phase A: per-tile histogram -> scan -> deterministic scatter (4B packed records).
// Phase B: one block per bucket, ds_add_f32 into 2KB LDS accumulator, one global
// write per node. Degree also derived from sorted records (kills k_count_deg).

#define BLK 256
#define NTILE 512
#define MAXB 512          // >= nbkt = ceil(n/256) = 391

// ---------- Phase A ----------

// A1: per-tile bucket histogram (LDS only), tile t writes table[t*nbkt + b]
__global__ void k_hist(const int* __restrict__ dst, int* __restrict__ table,
                       int e, int ept, int nbkt) {
    __shared__ int h[MAXB];
    int tile = blockIdx.x;
    for (int i = threadIdx.x; i < nbkt; i += BLK) h[i] = 0;
    __syncthreads();
    int lo = tile * ept;
    int hi = min(lo + ept, e);
    for (int i = lo + threadIdx.x; i < hi; i += BLK)
        atomicAdd(&h[dst[i] >> 8], 1);
    __syncthreads();
    for (int i = threadIdx.x; i < nbkt; i += BLK)
        table[tile * nbkt + i] = h[i];
}

// A2: turn per-tile counts into per-(tile,bucket) base offsets; bkt_off gets
// the bucket starts with sentinel bkt_off[nbkt] = e. One block of 512 threads.
__global__ void k_scan(int* __restrict__ table, int* __restrict__ bkt_off,
                       int ntile, int nbkt) {
    __shared__ int tot[MAXB];
    int b = threadIdx.x;
    if (b < nbkt) {
        int run = 0;
        for (int t = 0; t < ntile; ++t) {
            int c = table[t * nbkt + b];
            table[t * nbkt + b] = run;
            run += c;
        }
        tot[b] = run;
    }
    __syncthreads();
    if (threadIdx.x == 0) {
        int acc = 0;
        for (int i = 0; i < nbkt; ++i) { bkt_off[i] = acc; acc += tot[i]; }
        bkt_off[nbkt] = acc;
    }
    __syncthreads();
    if (b < nbkt) {
        int off = bkt_off[b];
        for (int t = 0; t < ntile; ++t) table[t * nbkt + b] += off;
    }
}

// A3: scatter edges into bucket-sorted order. Positions: per-tile base (table)
// + LDS cursor. Record = src | (dst_local << 17)  (src < 2^17, dl < 256).
__global__ void k_scatter(const int* __restrict__ src, const int* __restrict__ dst,
                          const int* __restrict__ table, unsigned* __restrict__ sorted,
                          int e, int ept, int nbkt) {
    __shared__ int cur[MAXB];
    int tile = blockIdx.x;
    for (int i = threadIdx.x; i < nbkt; i += BLK) cur[i] = table[tile * nbkt + i];
    __syncthreads();
    int lo = tile * ept;
    int hi = min(lo + ept, e);
    for (int i = lo + threadIdx.x; i < hi; i += BLK) {
        int d = dst[i];
        int s = src[i];
        int b = d >> 8;
        int dl = d & 255;
        int pos = atomicAdd(&cur[b], 1);        // LDS atomic
        sorted[pos] = (unsigned)s | ((unsigned)dl << 17);
    }
}

// A4: per-bucket degree count -> dinv = rsqrt(deg+1)
__global__ void k_dinv(const unsigned* __restrict__ sorted, const int* __restrict__ bkt_off,
                       float* __restrict__ dinv, int n) {
    __shared__ int cnt[256];
    int b = blockIdx.x;
    cnt[threadIdx.x] = 0;
    __syncthreads();
    int lo = bkt_off[b], hi = bkt_off[b + 1];
    for (int i = lo + threadIdx.x; i < hi; i += BLK)
        atomicAdd(&cnt[sorted[i] >> 17], 1);    // LDS atomic
    __syncthreads();
    int node = (b << 8) + threadIdx.x;
    if (node < n) dinv[node] = rsqrtf((float)cnt[threadIdx.x] + 1.0f);
}

// ---------- node-wise kernels ----------

// self-loop init: agg_x = dinv^2 * x
__global__ void k_self(const float* __restrict__ x, const float* __restrict__ dinv,
                       float* __restrict__ agg_x, int n) {
    int i = blockIdx.x * BLK + threadIdx.x;
    if (i < n) {
        float d = dinv[i];
        float s = d * d;
        float2 xv = ((const float2*)x)[i];
        ((float2*)agg_x)[i] = make_float2(s * xv.x, s * xv.y);
    }
}

// ---------- Phase B: per-bucket aggregation, LDS atomics only ----------

// agg[node] (pre-initialized with self term) += sum over edges dinv[s]*dinv[d]*feat[s]
__global__ void k_bucket_agg(const unsigned* __restrict__ sorted, const int* __restrict__ bkt_off,
                             const float* __restrict__ dinv, const float* __restrict__ feat,
                             float* __restrict__ agg, int n) {
    __shared__ float dloc[256];
    __shared__ float acc[512];
    int b = blockIdx.x;
    int node = (b << 8) + threadIdx.x;
    bool valid = node < n;
    dloc[threadIdx.x] = valid ? dinv[node] : 0.0f;
    float2 a0 = valid ? ((const float2*)agg)[node] : make_float2(0.f, 0.f);
    acc[2 * threadIdx.x]     = a0.x;
    acc[2 * threadIdx.x + 1] = a0.y;
    __syncthreads();
    int lo = bkt_off[b], hi = bkt_off[b + 1];
    for (int i = lo + threadIdx.x; i < hi; i += BLK) {
        unsigned p = sorted[i];
        int s  = (int)(p & 0x1FFFFu);
        int dl = (int)(p >> 17);
        float nrm = dinv[s] * dloc[dl];
        float2 f = ((const float2*)feat)[s];
        atomicAdd(&acc[2 * dl],     nrm * f.x);   // ds_add_f32
        atomicAdd(&acc[2 * dl + 1], nrm * f.y);
    }
    __syncthreads();
    if (valid)
        ((float2*)agg)[node] = make_float2(acc[2 * threadIdx.x], acc[2 * threadIdx.x + 1]);
}

// per node: h = relu(agg_x @ W1 + b1); g = h @ W2; agg_g init = dinv^2 * g
__global__ void k_mlp(const float* __restrict__ agg_x, const float* __restrict__ dinv,
                      const float* __restrict__ W1, const float* __restrict__ b1,
                      const float* __restrict__ W2,
                      float* __restrict__ g, float* __restrict__ agg_g, int n) {
    int i = blockIdx.x * BLK + threadIdx.x;
    if (i < n) {
        float2 a = ((const float2*)agg_x)[i];
        float g0 = 0.f, g1 = 0.f;
#pragma unroll
        for (int f = 0; f < 16; ++f) {
            float h = fmaf(a.x, W1[f], fmaf(a.y, W1[16 + f], b1[f]));
            h = fmaxf(h, 0.0f);
            g0 = fmaf(h, W2[2 * f + 0], g0);
            g1 = fmaf(h, W2[2 * f + 1], g1);
        }
        ((float2*)g)[i] = make_float2(g0, g1);
        float s = dinv[i] * dinv[i];
        ((float2*)agg_g)[i] = make_float2(s * g0, s * g1);
    }
}

__global__ void k_logsoftmax(const float* __restrict__ agg_g, const float* __restrict__ b2,
                             float* __restrict__ out, int n) {
    int i = blockIdx.x * BLK + threadIdx.x;
    if (i < n) {
        float2 z = ((const float2*)agg_g)[i];
        float z0 = z.x + b2[0];
        float z1 = z.y + b2[1];
        float m = fmaxf(z0, z1);
        float lse = m + logf(expf(z0 - m) + expf(z1 - m));
        ((float2*)out)[i] = make_float2(z0 - lse, z1 - lse);
    }
}

extern "C" void kernel_launch(void* const* d_in, const int* in_sizes, int n_in,
                              void* d_out, int out_size, void* d_ws, size_t ws_size,
                              hipStream_t stream) {
    const float* x  = (const float*)d_in[0];   // [n,2]
    const int*   ei = (const int*)d_in[1];     // [2,e] flat: row0=src, row1=dst
    const float* W1 = (const float*)d_in[2];   // [2,16]
    const float* b1 = (const float*)d_in[3];   // [16]
    const float* W2 = (const float*)d_in[4];   // [16,2]
    const float* b2 = (const float*)d_in[5];   // [2]
    float* out = (float*)d_out;                // [n,2]

    const int n = in_sizes[0] / 2;             // 100000
    const int e = in_sizes[1] / 2;             // 3200000
    const int* src = ei;
    const int* dst = ei + e;

    const int nbkt = (n + 255) >> 8;           // 391
    const int ept  = (e + NTILE - 1) / NTILE;  // 6250

    // ws layout (bytes, 256B-aligned regions):
    char* base = (char*)d_ws;
    size_t off = 0;
    auto take = [&](size_t bytes) { char* p = base + off; off += (bytes + 255) & ~(size_t)255; return p; };
    unsigned* sorted = (unsigned*)take((size_t)e * 4);            // 12.8 MB
    int*      table  = (int*)take((size_t)NTILE * MAXB * 4);      // 1 MB
    int*      bkt_off= (int*)take((size_t)(MAXB + 1) * 4);
    float*    dinv   = (float*)take((size_t)n * 4);
    float*    agg_x  = (float*)take((size_t)n * 8);
    float*    g      = (float*)take((size_t)n * 8);
    float*    agg_g  = (float*)take((size_t)n * 8);

    const int gn = (n + BLK - 1) / BLK;

    k_hist      <<<NTILE, BLK, 0, stream>>>(dst, table, e, ept, nbkt);
    k_scan      <<<1, MAXB, 0, stream>>>(table, bkt_off, NTILE, nbkt);
    k_scatter   <<<NTILE, BLK, 0, stream>>>(src, dst, table, sorted, e, ept, nbkt);
    k_dinv      <<<nbkt, BLK, 0, stream>>>(sorted, bkt_off, dinv, n);
    k_self      <<<gn, BLK, 0, stream>>>(x, dinv, agg_x, n);
    k_bucket_agg<<<nbkt, BLK, 0, stream>>>(sorted, bkt_off, dinv, x, agg_x, n);   // layer 1
    k_mlp       <<<gn, BLK, 0, stream>>>(agg_x, dinv, W1, b1, W2, g, agg_g, n);
    k_bucket_agg<<<nbkt, BLK, 0, stream>>>(sorted, bkt_off, dinv, g, agg_g, n);   // layer 2
    k_logsoftmax<<<gn, BLK, 0, stream>>>(agg_g, b2, out, n);
}

// Round 4
// 230.326 us; speedup vs baseline: 3.8468x; 1.8070x over previous
//
#include <hip/hip_runtime.h>
#include <math.h>

// GCN 2-layer, algebraically fused, ATOMIC-FREE (global):
//   L1: A_norm @ (x W1) + b1 == ((A_norm @ x) W1) + b1   -> aggregate 2-wide x
//   h  = relu(...)
//   L2: A_norm @ (h W2) + b2 == (A_norm @ (h W2)) + b2   -> aggregate 2-wide g = h@W2
//   out = log_softmax(...)
//
// R2: bucketed counting sort (256 nodes/bucket) + per-bucket LDS aggregation.
// R3: k_scan was 194us at 0.09% occupancy (serial 512-tile walk per thread).
//     Split into parallel per-column scan (391 blocks) + tiny total-scan;
//     scatter adds bkt_off at cursor load; k_self merged into k_dinv.

#define BLK 256
#define NTILE 512
#define MAXB 512          // >= nbkt = ceil(n/256) = 391

// ---------- Phase A ----------

// A1: per-tile bucket histogram (LDS only), tile t writes table[t*nbkt + b]
__global__ void k_hist(const int* __restrict__ dst, int* __restrict__ table,
                       int e, int ept, int nbkt) {
    __shared__ int h[MAXB];
    int tile = blockIdx.x;
    for (int i = threadIdx.x; i < nbkt; i += BLK) h[i] = 0;
    __syncthreads();
    int lo = tile * ept;
    int hi = min(lo + ept, e);
    for (int i = lo + threadIdx.x; i < hi; i += BLK)
        atomicAdd(&h[dst[i] >> 8], 1);
    __syncthreads();
    for (int i = threadIdx.x; i < nbkt; i += BLK)
        table[tile * nbkt + i] = h[i];
}

// A2a: per-bucket column scan. Block b: Hillis-Steele over the 512 tile counts
// of bucket b; table <- intra-column exclusive prefix; tot[b] <- column sum.
__global__ void k_scan_col(int* __restrict__ table, int* __restrict__ tot, int nbkt) {
    __shared__ int buf[NTILE];
    int b = blockIdx.x;
    int t = threadIdx.x;               // 512 threads, one per tile
    int v = table[t * nbkt + b];
    buf[t] = v;
    __syncthreads();
#pragma unroll
    for (int ofs = 1; ofs < NTILE; ofs <<= 1) {
        int add = (t >= ofs) ? buf[t - ofs] : 0;
        __syncthreads();
        buf[t] += add;
        __syncthreads();
    }
    table[t * nbkt + b] = buf[t] - v;  // exclusive
    if (t == NTILE - 1) tot[b] = buf[t];
}

// A2b: exclusive scan of 391 bucket totals -> bkt_off, sentinel at nbkt.
__global__ void k_scan_tot(const int* __restrict__ tot, int* __restrict__ bkt_off, int nbkt) {
    __shared__ int buf[MAXB];
    int t = threadIdx.x;               // 512 threads
    int v = (t < nbkt) ? tot[t] : 0;
    buf[t] = v;
    __syncthreads();
#pragma unroll
    for (int ofs = 1; ofs < MAXB; ofs <<= 1) {
        int add = (t >= ofs) ? buf[t - ofs] : 0;
        __syncthreads();
        buf[t] += add;
        __syncthreads();
    }
    if (t < nbkt) bkt_off[t] = buf[t] - v;
    if (t == nbkt - 1) bkt_off[nbkt] = buf[t];
}

// A3: scatter edges into bucket-sorted order. Positions: bkt_off[b] + per-tile
// intra-column base + LDS cursor. Record = src | (dst_local << 17).
__global__ void k_scatter(const int* __restrict__ src, const int* __restrict__ dst,
                          const int* __restrict__ table, const int* __restrict__ bkt_off,
                          unsigned* __restrict__ sorted, int e, int ept, int nbkt) {
    __shared__ int cur[MAXB];
    int tile = blockIdx.x;
    for (int i = threadIdx.x; i < nbkt; i += BLK)
        cur[i] = table[tile * nbkt + i] + bkt_off[i];
    __syncthreads();
    int lo = tile * ept;
    int hi = min(lo + ept, e);
    for (int i = lo + threadIdx.x; i < hi; i += BLK) {
        int d = dst[i];
        int s = src[i];
        int b = d >> 8;
        int dl = d & 255;
        int pos = atomicAdd(&cur[b], 1);        // LDS atomic
        sorted[pos] = (unsigned)s | ((unsigned)dl << 17);
    }
}

// A4: per-bucket degree count -> dinv = rsqrt(deg+1); also self-loop init
// agg_x = dinv^2 * x (merged former k_self).
__global__ void k_dinv(const unsigned* __restrict__ sorted, const int* __restrict__ bkt_off,
                       const float* __restrict__ x, float* __restrict__ dinv,
                       float* __restrict__ agg_x, int n) {
    __shared__ int cnt[256];
    int b = blockIdx.x;
    cnt[threadIdx.x] = 0;
    __syncthreads();
    int lo = bkt_off[b], hi = bkt_off[b + 1];
    for (int i = lo + threadIdx.x; i < hi; i += BLK)
        atomicAdd(&cnt[sorted[i] >> 17], 1);    // LDS atomic
    __syncthreads();
    int node = (b << 8) + threadIdx.x;
    if (node < n) {
        float d = rsqrtf((float)cnt[threadIdx.x] + 1.0f);
        dinv[node] = d;
        float s = d * d;
        float2 xv = ((const float2*)x)[node];
        ((float2*)agg_x)[node] = make_float2(s * xv.x, s * xv.y);
    }
}

// ---------- Phase B: per-bucket aggregation, LDS atomics only ----------

__global__ void k_bucket_agg(const unsigned* __restrict__ sorted, const int* __restrict__ bkt_off,
                             const float* __restrict__ dinv, const float* __restrict__ feat,
                             float* __restrict__ agg, int n) {
    __shared__ float dloc[256];
    __shared__ float acc[512];
    int b = blockIdx.x;
    int node = (b << 8) + threadIdx.x;
    bool valid = node < n;
    dloc[threadIdx.x] = valid ? dinv[node] : 0.0f;
    float2 a0 = valid ? ((const float2*)agg)[node] : make_float2(0.f, 0.f);
    acc[2 * threadIdx.x]     = a0.x;
    acc[2 * threadIdx.x + 1] = a0.y;
    __syncthreads();
    int lo = bkt_off[b], hi = bkt_off[b + 1];
    for (int i = lo + threadIdx.x; i < hi; i += BLK) {
        unsigned p = sorted[i];
        int s  = (int)(p & 0x1FFFFu);
        int dl = (int)(p >> 17);
        float nrm = dinv[s] * dloc[dl];
        float2 f = ((const float2*)feat)[s];
        atomicAdd(&acc[2 * dl],     nrm * f.x);   // ds_add_f32
        atomicAdd(&acc[2 * dl + 1], nrm * f.y);
    }
    __syncthreads();
    if (valid)
        ((float2*)agg)[node] = make_float2(acc[2 * threadIdx.x], acc[2 * threadIdx.x + 1]);
}

// per node: h = relu(agg_x @ W1 + b1); g = h @ W2; agg_g init = dinv^2 * g
__global__ void k_mlp(const float* __restrict__ agg_x, const float* __restrict__ dinv,
                      const float* __restrict__ W1, const float* __restrict__ b1,
                      const float* __restrict__ W2,
                      float* __restrict__ g, float* __restrict__ agg_g, int n) {
    int i = blockIdx.x * BLK + threadIdx.x;
    if (i < n) {
        float2 a = ((const float2*)agg_x)[i];
        float g0 = 0.f, g1 = 0.f;
#pragma unroll
        for (int f = 0; f < 16; ++f) {
            float h = fmaf(a.x, W1[f], fmaf(a.y, W1[16 + f], b1[f]));
            h = fmaxf(h, 0.0f);
            g0 = fmaf(h, W2[2 * f + 0], g0);
            g1 = fmaf(h, W2[2 * f + 1], g1);
        }
        ((float2*)g)[i] = make_float2(g0, g1);
        float s = dinv[i] * dinv[i];
        ((float2*)agg_g)[i] = make_float2(s * g0, s * g1);
    }
}

__global__ void k_logsoftmax(const float* __restrict__ agg_g, const float* __restrict__ b2,
                             float* __restrict__ out, int n) {
    int i = blockIdx.x * BLK + threadIdx.x;
    if (i < n) {
        float2 z = ((const float2*)agg_g)[i];
        float z0 = z.x + b2[0];
        float z1 = z.y + b2[1];
        float m = fmaxf(z0, z1);
        float lse = m + logf(expf(z0 - m) + expf(z1 - m));
        ((float2*)out)[i] = make_float2(z0 - lse, z1 - lse);
    }
}

extern "C" void kernel_launch(void* const* d_in, const int* in_sizes, int n_in,
                              void* d_out, int out_size, void* d_ws, size_t ws_size,
                              hipStream_t stream) {
    const float* x  = (const float*)d_in[0];   // [n,2]
    const int*   ei = (const int*)d_in[1];     // [2,e] flat: row0=src, row1=dst
    const float* W1 = (const float*)d_in[2];   // [2,16]
    const float* b1 = (const float*)d_in[3];   // [16]
    const float* W2 = (const float*)d_in[4];   // [16,2]
    const float* b2 = (const float*)d_in[5];   // [2]
    float* out = (float*)d_out;                // [n,2]

    const int n = in_sizes[0] / 2;             // 100000
    const int e = in_sizes[1] / 2;             // 3200000
    const int* src = ei;
    const int* dst = ei + e;

    const int nbkt = (n + 255) >> 8;           // 391
    const int ept  = (e + NTILE - 1) / NTILE;  // 6250

    // ws layout:
    char* base = (char*)d_ws;
    size_t off = 0;
    auto take = [&](size_t bytes) { char* p = base + off; off += (bytes + 255) & ~(size_t)255; return p; };
    unsigned* sorted  = (unsigned*)take((size_t)e * 4);            // 12.8 MB
    int*      table   = (int*)take((size_t)NTILE * MAXB * 4);      // 1 MB
    int*      tot     = (int*)take((size_t)MAXB * 4);
    int*      bkt_off = (int*)take((size_t)(MAXB + 1) * 4);
    float*    dinv    = (float*)take((size_t)n * 4);
    float*    agg_x   = (float*)take((size_t)n * 8);
    float*    g       = (float*)take((size_t)n * 8);
    float*    agg_g   = (float*)take((size_t)n * 8);

    const int gn = (n + BLK - 1) / BLK;

    k_hist      <<<NTILE, BLK, 0, stream>>>(dst, table, e, ept, nbkt);
    k_scan_col  <<<nbkt, NTILE, 0, stream>>>(table, tot, nbkt);
    k_scan_tot  <<<1, MAXB, 0, stream>>>(tot, bkt_off, nbkt);
    k_scatter   <<<NTILE, BLK, 0, stream>>>(src, dst, table, bkt_off, sorted, e, ept, nbkt);
    k_dinv      <<<nbkt, BLK, 0, stream>>>(sorted, bkt_off, x, dinv, agg_x, n);
    k_bucket_agg<<<nbkt, BLK, 0, stream>>>(sorted, bkt_off, dinv, x, agg_x, n);   // layer 1
    k_mlp       <<<gn, BLK, 0, stream>>>(agg_x, dinv, W1, b1, W2, g, agg_g, n);
    k_bucket_agg<<<nbkt, BLK, 0, stream>>>(sorted, bkt_off, dinv, g, agg_g, n);   // layer 2
    k_logsoftmax<<<gn, BLK, 0, stream>>>(agg_g, b2, out, n);
}

// Round 5
// 203.729 us; speedup vs baseline: 4.3489x; 1.1306x over previous
//
#include <hip/hip_runtime.h>
#include <math.h>

// GCN 2-layer, algebraically fused, ATOMIC-FREE (global):
//   agg_x[d] = dinv[d]*(sum_{s in N(d)} xp[s] + xp[d]),  xp = dinv*x   (premultiplied!)
//   h = relu(agg_x@W1+b1); g = h@W2; gp = dinv*g
//   out = log_softmax(dinv[d]*(sum gp[s] + gp[d]) + b2)
//
// R2: bucketed counting sort (256 nodes/bucket) + per-bucket LDS aggregation.
// R3: parallel scan (serial k_scan was 47% of runtime at 0.09% occupancy).
// R4: (a) 8-way sliced aggregation w/ partial buffers — bucket_agg was 48us at
//     12.8% occupancy (391 blocks, latency-bound); (b) dinv premultiplied into
//     features — kills the dinv[s] gather in the edge loop; (c) scatter stages
//     the tile in LDS (counting sort, counts derived from scan table) and
//     writes bucket-contiguous runs — was 5x write amplification (68MB/12.8MB).

#define BLK 256
#define NTILE 1024
#define EPT 3200          // >= ceil(e/NTILE) = 3125
#define MAXB 512          // >= nbkt = ceil(n/256) = 391
#define NS 8              // slices per bucket in Phase B

// ---------- Phase A ----------

// A1: per-tile bucket histogram -> table[tile*nbkt + b]
__global__ void k_hist(const int* __restrict__ dst, int* __restrict__ table,
                       int e, int ept, int nbkt) {
    __shared__ int h[MAXB];
    int tile = blockIdx.x;
    for (int i = threadIdx.x; i < MAXB; i += BLK) h[i] = 0;
    __syncthreads();
    int lo = tile * ept;
    int hi = min(lo + ept, e);
    for (int i = lo + threadIdx.x; i < hi; i += BLK)
        atomicAdd(&h[dst[i] >> 8], 1);
    __syncthreads();
    for (int i = threadIdx.x; i < nbkt; i += BLK)
        table[tile * nbkt + i] = h[i];
}

// A2a: per-bucket column scan over NTILE tiles (block = NTILE threads).
// table <- intra-column EXCLUSIVE prefix; tot[b] <- column sum.
__global__ void k_scan_col(int* __restrict__ table, int* __restrict__ tot, int nbkt) {
    __shared__ int buf[NTILE];
    int b = blockIdx.x;
    int t = threadIdx.x;
    int v = table[t * nbkt + b];
    buf[t] = v;
    __syncthreads();
#pragma unroll
    for (int ofs = 1; ofs < NTILE; ofs <<= 1) {
        int add = (t >= ofs) ? buf[t - ofs] : 0;
        __syncthreads();
        buf[t] += add;
        __syncthreads();
    }
    table[t * nbkt + b] = buf[t] - v;
    if (t == NTILE - 1) tot[b] = buf[t];
}

// A2b: exclusive scan of bucket totals -> bkt_off (+ sentinel).
__global__ void k_scan_tot(const int* __restrict__ tot, int* __restrict__ bkt_off, int nbkt) {
    __shared__ int buf[MAXB];
    int t = threadIdx.x;               // MAXB threads
    int v = (t < nbkt) ? tot[t] : 0;
    buf[t] = v;
    __syncthreads();
#pragma unroll
    for (int ofs = 1; ofs < MAXB; ofs <<= 1) {
        int add = (t >= ofs) ? buf[t - ofs] : 0;
        __syncthreads();
        buf[t] += add;
        __syncthreads();
    }
    if (t < nbkt) bkt_off[t] = buf[t] - v;
    if (t == nbkt - 1) bkt_off[nbkt] = buf[t];
}

// A3: staged scatter. Local counting sort of the tile in LDS, then
// bucket-contiguous global writes. Record = src | (dst_local << 17).
__global__ void k_scatter(const int* __restrict__ src, const int* __restrict__ dst,
                          const int* __restrict__ table, const int* __restrict__ tot,
                          const int* __restrict__ bkt_off, unsigned* __restrict__ sorted,
                          int e, int ept, int nbkt) {
    __shared__ int off[MAXB];      // local exclusive offsets (pads = total)
    __shared__ int cur[MAXB];
    __shared__ int base2[MAXB];    // global base - local off
    __shared__ unsigned stage[EPT];
    int tile = blockIdx.x;
    int lo = tile * ept;
    int hi = min(lo + ept, e);
    int total = hi - lo;
    int t = threadIdx.x;

    // local counts (free: derived from scan table), global bases
    for (int b = t; b < MAXB; b += BLK) {
        int c = 0;
        if (b < nbkt) {
            int base = table[tile * nbkt + b];
            int next = (tile < NTILE - 1) ? table[(tile + 1) * nbkt + b] : tot[b];
            c = next - base;
            base2[b] = bkt_off[b] + base;
        }
        off[b] = c;
    }
    __syncthreads();
    // Hillis-Steele inclusive scan over MAXB entries, 2 per thread
    int c0 = off[t], c1 = off[t + BLK];
#pragma unroll
    for (int ofs = 1; ofs < MAXB; ofs <<= 1) {
        int a0 = (t >= ofs) ? off[t - ofs] : 0;
        int a1 = off[t + BLK - ofs];
        __syncthreads();
        off[t] += a0;
        off[t + BLK] += a1;
        __syncthreads();
    }
    // inclusive -> exclusive
    int e0 = off[t] - c0, e1 = off[t + BLK] - c1;
    __syncthreads();
    off[t] = e0; off[t + BLK] = e1;
    __syncthreads();
    for (int b = t; b < nbkt; b += BLK) {
        base2[b] -= off[b];
        cur[b] = off[b];
    }
    __syncthreads();
    // pass 2: place records into LDS stage in bucket order
    for (int i = lo + t; i < hi; i += BLK) {
        int d = dst[i];
        int s = src[i];
        int b = d >> 8;
        int pos = atomicAdd(&cur[b], 1);        // LDS atomic
        stage[pos] = (unsigned)s | ((unsigned)(d & 255) << 17);
    }
    __syncthreads();
    // pass 3: bucket-contiguous global writes (binary search bucket of j)
    for (int j = t; j < total; j += BLK) {
        int loB = 0, hiB = MAXB;
        while (hiB - loB > 1) {
            int mid = (loB + hiB) >> 1;
            if (off[mid] <= j) loB = mid; else hiB = mid;
        }
        sorted[base2[loB] + j] = stage[j];
    }
}

// ---------- degree ----------

// sliced per-bucket degree count -> int partials
__global__ void k_deg_slice(const unsigned* __restrict__ sorted, const int* __restrict__ bkt_off,
                            int* __restrict__ pdeg) {
    __shared__ int cnt[256];
    int b = blockIdx.x, s = blockIdx.y;
    cnt[threadIdx.x] = 0;
    __syncthreads();
    int lo = bkt_off[b], hi = bkt_off[b + 1];
    int len = hi - lo;
    int slo = lo + (int)((long long)len * s / NS);
    int shi = lo + (int)((long long)len * (s + 1) / NS);
    for (int i = slo + threadIdx.x; i < shi; i += BLK)
        atomicAdd(&cnt[sorted[i] >> 17], 1);    // LDS atomic
    __syncthreads();
    pdeg[(b * NS + s) * 256 + threadIdx.x] = cnt[threadIdx.x];
}

// merge degree partials -> dinv, xp = dinv * x
__global__ void k_dinv_merge(const int* __restrict__ pdeg, const float* __restrict__ x,
                             float* __restrict__ dinv, float* __restrict__ xp, int n) {
    int i = blockIdx.x * BLK + threadIdx.x;
    if (i >= n) return;
    int b = i >> 8, t = i & 255;
    int deg = 1;  // self loop
#pragma unroll
    for (int s = 0; s < NS; ++s) deg += pdeg[(b * NS + s) * 256 + t];
    float d = rsqrtf((float)deg);
    dinv[i] = d;
    float2 xv = ((const float2*)x)[i];
    ((float2*)xp)[i] = make_float2(d * xv.x, d * xv.y);
}

// ---------- Phase B: sliced aggregation of premultiplied features ----------

__global__ void k_agg_slice(const unsigned* __restrict__ sorted, const int* __restrict__ bkt_off,
                            const float* __restrict__ featp, float* __restrict__ partial) {
    __shared__ float acc[512];
    int b = blockIdx.x, s = blockIdx.y;
    acc[threadIdx.x] = 0.f;
    acc[threadIdx.x + 256] = 0.f;
    __syncthreads();
    int lo = bkt_off[b], hi = bkt_off[b + 1];
    int len = hi - lo;
    int slo = lo + (int)((long long)len * s / NS);
    int shi = lo + (int)((long long)len * (s + 1) / NS);
    for (int i = slo + threadIdx.x; i < shi; i += BLK) {
        unsigned p = sorted[i];
        float2 f = ((const float2*)featp)[p & 0x1FFFFu];
        int dl = (int)(p >> 17);
        atomicAdd(&acc[2 * dl],     f.x);   // ds_add_f32
        atomicAdd(&acc[2 * dl + 1], f.y);
    }
    __syncthreads();
    float2* out = (float2*)&partial[(size_t)(b * NS + s) * 512];
    out[threadIdx.x] = make_float2(acc[2 * threadIdx.x], acc[2 * threadIdx.x + 1]);
}

// merge L1 partials + self, MLP, output gp = dinv * (h@W2)
__global__ void k_mlp_merge(const float* __restrict__ partial, const float* __restrict__ dinv,
                            const float* __restrict__ xp,
                            const float* __restrict__ W1, const float* __restrict__ b1,
                            const float* __restrict__ W2, float* __restrict__ gp, int n) {
    int i = blockIdx.x * BLK + threadIdx.x;
    if (i >= n) return;
    int b = i >> 8, t = i & 255;
    float2 xv = ((const float2*)xp)[i];
    float ax = xv.x, ay = xv.y;
#pragma unroll
    for (int s = 0; s < NS; ++s) {
        float2 p = ((const float2*)&partial[(size_t)(b * NS + s) * 512])[t];
        ax += p.x; ay += p.y;
    }
    float d = dinv[i];
    ax *= d; ay *= d;
    float g0 = 0.f, g1 = 0.f;
#pragma unroll
    for (int f = 0; f < 16; ++f) {
        float h = fmaf(ax, W1[f], fmaf(ay, W1[16 + f], b1[f]));
        h = fmaxf(h, 0.0f);
        g0 = fmaf(h, W2[2 * f + 0], g0);
        g1 = fmaf(h, W2[2 * f + 1], g1);
    }
    ((float2*)gp)[i] = make_float2(d * g0, d * g1);
}

// merge L2 partials + self + bias, log_softmax
__global__ void k_final(const float* __restrict__ partial, const float* __restrict__ dinv,
                        const float* __restrict__ gp, const float* __restrict__ b2,
                        float* __restrict__ out, int n) {
    int i = blockIdx.x * BLK + threadIdx.x;
    if (i >= n) return;
    int b = i >> 8, t = i & 255;
    float2 gv = ((const float2*)gp)[i];
    float ax = gv.x, ay = gv.y;
#pragma unroll
    for (int s = 0; s < NS; ++s) {
        float2 p = ((const float2*)&partial[(size_t)(b * NS + s) * 512])[t];
        ax += p.x; ay += p.y;
    }
    float d = dinv[i];
    float z0 = d * ax + b2[0];
    float z1 = d * ay + b2[1];
    float m = fmaxf(z0, z1);
    float lse = m + logf(expf(z0 - m) + expf(z1 - m));
    ((float2*)out)[i] = make_float2(z0 - lse, z1 - lse);
}

extern "C" void kernel_launch(void* const* d_in, const int* in_sizes, int n_in,
                              void* d_out, int out_size, void* d_ws, size_t ws_size,
                              hipStream_t stream) {
    const float* x  = (const float*)d_in[0];   // [n,2]
    const int*   ei = (const int*)d_in[1];     // [2,e]: row0=src, row1=dst
    const float* W1 = (const float*)d_in[2];   // [2,16]
    const float* b1 = (const float*)d_in[3];   // [16]
    const float* W2 = (const float*)d_in[4];   // [16,2]
    const float* b2 = (const float*)d_in[5];   // [2]
    float* out = (float*)d_out;                // [n,2]

    const int n = in_sizes[0] / 2;             // 100000
    const int e = in_sizes[1] / 2;             // 3200000
    const int* src = ei;
    const int* dst = ei + e;

    const int nbkt = (n + 255) >> 8;           // 391
    const int ept  = (e + NTILE - 1) / NTILE;  // 3125

    // ws layout; pdeg aliases partial (pdeg dead before partial first written)
    char* base = (char*)d_ws;
    size_t off = 0;
    auto take = [&](size_t bytes) { char* p = base + off; off += (bytes + 255) & ~(size_t)255; return p; };
    unsigned* sorted  = (unsigned*)take((size_t)e * 4);                   // 12.8 MB
    int*      table   = (int*)take((size_t)NTILE * nbkt * 4);             // 1.6 MB
    int*      tot     = (int*)take((size_t)MAXB * 4);
    int*      bkt_off = (int*)take((size_t)(MAXB + 1) * 4);
    float*    partial = (float*)take((size_t)nbkt * NS * 512 * 4);        // 6.4 MB (also pdeg)
    int*      pdeg    = (int*)partial;
    float*    dinv    = (float*)take((size_t)n * 4);
    float*    xp      = (float*)take((size_t)n * 8);
    float*    gp      = (float*)take((size_t)n * 8);

    const int gn = (n + BLK - 1) / BLK;
    dim3 gslice(nbkt, NS);

    k_hist      <<<NTILE, BLK, 0, stream>>>(dst, table, e, ept, nbkt);
    k_scan_col  <<<nbkt, NTILE, 0, stream>>>(table, tot, nbkt);
    k_scan_tot  <<<1, MAXB, 0, stream>>>(tot, bkt_off, nbkt);
    k_scatter   <<<NTILE, BLK, 0, stream>>>(src, dst, table, tot, bkt_off, sorted, e, ept, nbkt);
    k_deg_slice <<<gslice, BLK, 0, stream>>>(sorted, bkt_off, pdeg);
    k_dinv_merge<<<gn, BLK, 0, stream>>>(pdeg, x, dinv, xp, n);
    k_agg_slice <<<gslice, BLK, 0, stream>>>(sorted, bkt_off, xp, partial);   // layer 1
    k_mlp_merge <<<gn, BLK, 0, stream>>>(partial, dinv, xp, W1, b1, W2, gp, n);
    k_agg_slice <<<gslice, BLK, 0, stream>>>(sorted, bkt_off, gp, partial);   // layer 2
    k_final     <<<gn, BLK, 0, stream>>>(partial, dinv, gp, b2, out, n);
}

// Round 6
// 186.809 us; speedup vs baseline: 4.7428x; 1.0906x over previous
//
#include <hip/hip_runtime.h>
#include <math.h>

// GCN 2-layer, algebraically fused, ATOMIC-FREE (global):
//   agg_x[d] = dinv[d]*(sum_{s in N(d)} xp[s] + xp[d]),  xp = dinv*x
//   h = relu(agg_x@W1+b1); g = h@W2; gp = dinv*g
//   out = log_softmax(dinv[d]*(sum gp[s] + gp[d]) + b2)
//
// R2: bucketed counting sort (256 nodes/bucket) + per-bucket LDS aggregation.
// R3: parallel scan (serial scan was 47% of runtime).
// R4: 8-way sliced aggregation, premultiplied dinv, staged scatter.
// R5: (a) stage_b[] kills the per-record binary search in scatter pass 3;
//     (b) all LDS Hillis-Steele scans -> __shfl_up wave scans (2 syncs);
//     (c) NTILE 512 + int4 edge-list loads (halves table, 4x fewer load issues,
//         64B bucket runs for coalesced scatter writes).

#define BLK 256
#define NTILE 512
#define EPTMAX 6400        // >= runtime ept (6252), multiple of 4
#define MAXB 512           // >= nbkt = 391
#define NS 8               // slices per bucket in Phase B

// ---------- Phase A ----------

// A1: per-tile bucket histogram -> table[tile*nbkt + b]
__global__ void k_hist(const int* __restrict__ dst, int* __restrict__ table,
                       int e, int ept, int nbkt) {
    __shared__ int h[MAXB];
    int tile = blockIdx.x;
    for (int i = threadIdx.x; i < MAXB; i += BLK) h[i] = 0;
    __syncthreads();
    int lo = tile * ept;
    int hi = min(lo + ept, e);
    // ept%4==0, e%4==0 -> (hi-lo)%4==0 and lo 16B-aligned
    for (int i = lo + 4 * threadIdx.x; i < hi; i += 4 * BLK) {
        int4 d4 = *(const int4*)(dst + i);
        atomicAdd(&h[d4.x >> 8], 1);
        atomicAdd(&h[d4.y >> 8], 1);
        atomicAdd(&h[d4.z >> 8], 1);
        atomicAdd(&h[d4.w >> 8], 1);
    }
    __syncthreads();
    for (int i = threadIdx.x; i < nbkt; i += BLK)
        table[tile * nbkt + i] = h[i];
}

// A2a: per-bucket column scan over NTILE tiles (block = NTILE threads).
// table <- intra-column EXCLUSIVE prefix; tot[b] <- column sum. Shuffle scan.
__global__ void k_scan_col(int* __restrict__ table, int* __restrict__ tot, int nbkt) {
    __shared__ int wsum[NTILE / 64];
    int b = blockIdx.x;
    int t = threadIdx.x;
    int v = table[t * nbkt + b];
    int x = v;
    int lane = t & 63;
#pragma unroll
    for (int ofs = 1; ofs < 64; ofs <<= 1) {
        int y = __shfl_up(x, ofs, 64);
        if (lane >= ofs) x += y;
    }
    if (lane == 63) wsum[t >> 6] = x;
    __syncthreads();
    if (t < NTILE / 64) {
        int s = wsum[t];
        int w = s;
#pragma unroll
        for (int ofs = 1; ofs < NTILE / 64; ofs <<= 1) {
            int y = __shfl_up(w, ofs, 64);
            if (t >= ofs) w += y;
        }
        wsum[t] = w - s;   // exclusive wave offset
    }
    __syncthreads();
    int incl = x + wsum[t >> 6];
    table[t * nbkt + b] = incl - v;
    if (t == NTILE - 1) tot[b] = incl;
}

// A2b: exclusive scan of bucket totals -> bkt_off (+ sentinel). Shuffle scan.
__global__ void k_scan_tot(const int* __restrict__ tot, int* __restrict__ bkt_off, int nbkt) {
    __shared__ int wsum[MAXB / 64];
    int t = threadIdx.x;               // MAXB threads
    int v = (t < nbkt) ? tot[t] : 0;
    int x = v;
    int lane = t & 63;
#pragma unroll
    for (int ofs = 1; ofs < 64; ofs <<= 1) {
        int y = __shfl_up(x, ofs, 64);
        if (lane >= ofs) x += y;
    }
    if (lane == 63) wsum[t >> 6] = x;
    __syncthreads();
    if (t < MAXB / 64) {
        int s = wsum[t];
        int w = s;
#pragma unroll
        for (int ofs = 1; ofs < MAXB / 64; ofs <<= 1) {
            int y = __shfl_up(w, ofs, 64);
            if (t >= ofs) w += y;
        }
        wsum[t] = w - s;
    }
    __syncthreads();
    int incl = x + wsum[t >> 6];
    if (t < nbkt) bkt_off[t] = incl - v;
    if (t == nbkt - 1) bkt_off[nbkt] = incl;
}

// A3: staged scatter. Local counting sort of the tile in LDS, then
// bucket-contiguous global writes. Record = src | (dst_local << 17).
// stage_b[] remembers each slot's bucket (kills pass-3 binary search).
__global__ void k_scatter(const int* __restrict__ src, const int* __restrict__ dst,
                          const int* __restrict__ table, const int* __restrict__ tot,
                          const int* __restrict__ bkt_off, unsigned* __restrict__ sorted,
                          int e, int ept, int nbkt) {
    __shared__ int cur[MAXB];
    __shared__ int base2[MAXB];            // global base minus local offset
    __shared__ unsigned stage[EPTMAX];
    __shared__ unsigned short stage_b[EPTMAX];
    __shared__ int wpart[BLK / 64];
    int tile = blockIdx.x;
    int t = threadIdx.x;
    int lo = tile * ept;
    int hi = min(lo + ept, e);
    int total = hi - lo;

    // local counts for buckets 2t, 2t+1 (derived from scan table), global bases
    int b0 = 2 * t, b1 = 2 * t + 1;
    int c0 = 0, c1 = 0, g0 = 0, g1 = 0;
    if (b0 < nbkt) {
        int base = table[tile * nbkt + b0];
        int next = (tile < NTILE - 1) ? table[(tile + 1) * nbkt + b0] : tot[b0];
        c0 = next - base;
        g0 = bkt_off[b0] + base;
    }
    if (b1 < nbkt) {
        int base = table[tile * nbkt + b1];
        int next = (tile < NTILE - 1) ? table[(tile + 1) * nbkt + b1] : tot[b1];
        c1 = next - base;
        g1 = bkt_off[b1] + base;
    }
    // shuffle scan of pair sums -> local exclusive offsets
    int p = c0 + c1;
    int x = p;
    int lane = t & 63;
#pragma unroll
    for (int ofs = 1; ofs < 64; ofs <<= 1) {
        int y = __shfl_up(x, ofs, 64);
        if (lane >= ofs) x += y;
    }
    if (lane == 63) wpart[t >> 6] = x;
    __syncthreads();
    if (t < BLK / 64) {
        int s = wpart[t];
        int w = s;
#pragma unroll
        for (int ofs = 1; ofs < BLK / 64; ofs <<= 1) {
            int y = __shfl_up(w, ofs, 64);
            if (t >= ofs) w += y;
        }
        wpart[t] = w - s;
    }
    __syncthreads();
    int E = x + wpart[t >> 6] - p;   // exclusive offset of bucket b0
    cur[b0] = E;
    cur[b1] = E + c0;
    if (b0 < nbkt) base2[b0] = g0 - E;
    if (b1 < nbkt) base2[b1] = g1 - (E + c0);
    __syncthreads();

    // pass 2: place records into LDS stage in bucket order (int4 loads)
    for (int i = lo + 4 * t; i < hi; i += 4 * BLK) {
        int4 s4 = *(const int4*)(src + i);
        int4 d4 = *(const int4*)(dst + i);
        int b, pos;
        b = d4.x >> 8; pos = atomicAdd(&cur[b], 1);
        stage[pos] = (unsigned)s4.x | ((unsigned)(d4.x & 255) << 17); stage_b[pos] = (unsigned short)b;
        b = d4.y >> 8; pos = atomicAdd(&cur[b], 1);
        stage[pos] = (unsigned)s4.y | ((unsigned)(d4.y & 255) << 17); stage_b[pos] = (unsigned short)b;
        b = d4.z >> 8; pos = atomicAdd(&cur[b], 1);
        stage[pos] = (unsigned)s4.z | ((unsigned)(d4.z & 255) << 17); stage_b[pos] = (unsigned short)b;
        b = d4.w >> 8; pos = atomicAdd(&cur[b], 1);
        stage[pos] = (unsigned)s4.w | ((unsigned)(d4.w & 255) << 17); stage_b[pos] = (unsigned short)b;
    }
    __syncthreads();
    // pass 3: bucket-contiguous global writes
    for (int j = t; j < total; j += BLK) {
        int b = stage_b[j];
        sorted[base2[b] + j] = stage[j];
    }
}

// ---------- degree ----------

__global__ void k_deg_slice(const unsigned* __restrict__ sorted, const int* __restrict__ bkt_off,
                            int* __restrict__ pdeg) {
    __shared__ int cnt[256];
    int b = blockIdx.x, s = blockIdx.y;
    cnt[threadIdx.x] = 0;
    __syncthreads();
    int lo = bkt_off[b], hi = bkt_off[b + 1];
    int len = hi - lo;
    int slo = lo + (int)((long long)len * s / NS);
    int shi = lo + (int)((long long)len * (s + 1) / NS);
    for (int i = slo + threadIdx.x; i < shi; i += BLK)
        atomicAdd(&cnt[sorted[i] >> 17], 1);    // LDS atomic
    __syncthreads();
    pdeg[(b * NS + s) * 256 + threadIdx.x] = cnt[threadIdx.x];
}

__global__ void k_dinv_merge(const int* __restrict__ pdeg, const float* __restrict__ x,
                             float* __restrict__ dinv, float* __restrict__ xp, int n) {
    int i = blockIdx.x * BLK + threadIdx.x;
    if (i >= n) return;
    int b = i >> 8, t = i & 255;
    int deg = 1;  // self loop
#pragma unroll
    for (int s = 0; s < NS; ++s) deg += pdeg[(b * NS + s) * 256 + t];
    float d = rsqrtf((float)deg);
    dinv[i] = d;
    float2 xv = ((const float2*)x)[i];
    ((float2*)xp)[i] = make_float2(d * xv.x, d * xv.y);
}

// ---------- Phase B: sliced aggregation of premultiplied features ----------

__global__ void k_agg_slice(const unsigned* __restrict__ sorted, const int* __restrict__ bkt_off,
                            const float* __restrict__ featp, float* __restrict__ partial) {
    __shared__ float acc[512];
    int b = blockIdx.x, s = blockIdx.y;
    acc[threadIdx.x] = 0.f;
    acc[threadIdx.x + 256] = 0.f;
    __syncthreads();
    int lo = bkt_off[b], hi = bkt_off[b + 1];
    int len = hi - lo;
    int slo = lo + (int)((long long)len * s / NS);
    int shi = lo + (int)((long long)len * (s + 1) / NS);
    for (int i = slo + threadIdx.x; i < shi; i += BLK) {
        unsigned p = sorted[i];
        float2 f = ((const float2*)featp)[p & 0x1FFFFu];
        int dl = (int)(p >> 17);
        atomicAdd(&acc[2 * dl],     f.x);   // ds_add_f32
        atomicAdd(&acc[2 * dl + 1], f.y);
    }
    __syncthreads();
    float2* out = (float2*)&partial[(size_t)(b * NS + s) * 512];
    out[threadIdx.x] = make_float2(acc[2 * threadIdx.x], acc[2 * threadIdx.x + 1]);
}

__global__ void k_mlp_merge(const float* __restrict__ partial, const float* __restrict__ dinv,
                            const float* __restrict__ xp,
                            const float* __restrict__ W1, const float* __restrict__ b1,
                            const float* __restrict__ W2, float* __restrict__ gp, int n) {
    int i = blockIdx.x * BLK + threadIdx.x;
    if (i >= n) return;
    int b = i >> 8, t = i & 255;
    float2 xv = ((const float2*)xp)[i];
    float ax = xv.x, ay = xv.y;
#pragma unroll
    for (int s = 0; s < NS; ++s) {
        float2 p = ((const float2*)&partial[(size_t)(b * NS + s) * 512])[t];
        ax += p.x; ay += p.y;
    }
    float d = dinv[i];
    ax *= d; ay *= d;
    float g0 = 0.f, g1 = 0.f;
#pragma unroll
    for (int f = 0; f < 16; ++f) {
        float h = fmaf(ax, W1[f], fmaf(ay, W1[16 + f], b1[f]));
        h = fmaxf(h, 0.0f);
        g0 = fmaf(h, W2[2 * f + 0], g0);
        g1 = fmaf(h, W2[2 * f + 1], g1);
    }
    ((float2*)gp)[i] = make_float2(d * g0, d * g1);
}

__global__ void k_final(const float* __restrict__ partial, const float* __restrict__ dinv,
                        const float* __restrict__ gp, const float* __restrict__ b2,
                        float* __restrict__ out, int n) {
    int i = blockIdx.x * BLK + threadIdx.x;
    if (i >= n) return;
    int b = i >> 8, t = i & 255;
    float2 gv = ((const float2*)gp)[i];
    float ax = gv.x, ay = gv.y;
#pragma unroll
    for (int s = 0; s < NS; ++s) {
        float2 p = ((const float2*)&partial[(size_t)(b * NS + s) * 512])[t];
        ax += p.x; ay += p.y;
    }
    float d = dinv[i];
    float z0 = d * ax + b2[0];
    float z1 = d * ay + b2[1];
    float m = fmaxf(z0, z1);
    float lse = m + logf(expf(z0 - m) + expf(z1 - m));
    ((float2*)out)[i] = make_float2(z0 - lse, z1 - lse);
}

extern "C" void kernel_launch(void* const* d_in, const int* in_sizes, int n_in,
                              void* d_out, int out_size, void* d_ws, size_t ws_size,
                              hipStream_t stream) {
    const float* x  = (const float*)d_in[0];   // [n,2]
    const int*   ei = (const int*)d_in[1];     // [2,e]: row0=src, row1=dst
    const float* W1 = (const float*)d_in[2];   // [2,16]
    const float* b1 = (const float*)d_in[3];   // [16]
    const float* W2 = (const float*)d_in[4];   // [16,2]
    const float* b2 = (const float*)d_in[5];   // [2]
    float* out = (float*)d_out;                // [n,2]

    const int n = in_sizes[0] / 2;             // 100000
    const int e = in_sizes[1] / 2;             // 3200000
    const int* src = ei;
    const int* dst = ei + e;

    const int nbkt = (n + 255) >> 8;           // 391
    int ept = (((e + NTILE - 1) / NTILE) + 3) & ~3;   // 6252, %4==0, <= EPTMAX

    // ws layout; pdeg aliases partial (pdeg dead before partial first written)
    char* base = (char*)d_ws;
    size_t off = 0;
    auto take = [&](size_t bytes) { char* p = base + off; off += (bytes + 255) & ~(size_t)255; return p; };
    unsigned* sorted  = (unsigned*)take((size_t)e * 4);                   // 12.8 MB
    int*      table   = (int*)take((size_t)NTILE * nbkt * 4);             // 0.8 MB
    int*      tot     = (int*)take((size_t)MAXB * 4);
    int*      bkt_off = (int*)take((size_t)(MAXB + 1) * 4);
    float*    partial = (float*)take((size_t)nbkt * NS * 512 * 4);        // 6.4 MB (also pdeg)
    int*      pdeg    = (int*)partial;
    float*    dinv    = (float*)take((size_t)n * 4);
    float*    xp      = (float*)take((size_t)n * 8);
    float*    gp      = (float*)take((size_t)n * 8);

    const int gn = (n + BLK - 1) / BLK;
    dim3 gslice(nbkt, NS);

    k_hist      <<<NTILE, BLK, 0, stream>>>(dst, table, e, ept, nbkt);
    k_scan_col  <<<nbkt, NTILE, 0, stream>>>(table, tot, nbkt);
    k_scan_tot  <<<1, MAXB, 0, stream>>>(tot, bkt_off, nbkt);
    k_scatter   <<<NTILE, BLK, 0, stream>>>(src, dst, table, tot, bkt_off, sorted, e, ept, nbkt);
    k_deg_slice <<<gslice, BLK, 0, stream>>>(sorted, bkt_off, pdeg);
    k_dinv_merge<<<gn, BLK, 0, stream>>>(pdeg, x, dinv, xp, n);
    k_agg_slice <<<gslice, BLK, 0, stream>>>(sorted, bkt_off, xp, partial);   // layer 1
    k_mlp_merge <<<gn, BLK, 0, stream>>>(partial, dinv, xp, W1, b1, W2, gp, n);
    k_agg_slice <<<gslice, BLK, 0, stream>>>(sorted, bkt_off, gp, partial);   // layer 2
    k_final     <<<gn, BLK, 0, stream>>>(partial, dinv, gp, b2, out, n);
}